// Round 2
// 674.707 us; speedup vs baseline: 1.0119x; 1.0119x over previous
//
#include <hip/hip_runtime.h>

// SmallSNN: T=50, B=128, ni=16384, nh=256, no=11
// Pipeline: convert_w1 (one-time fp32 -> f16 hi/lo limb split of W1)
//        -> gemm1_mfma (f16x2-limb split-fp32 MFMA, split-K=8,
//                       XOR-swizzled LDS + global_load_lds B staging)
//        -> scan1 (split-K reduce + bias + membrane recursion -> spk1)
//        -> gemm2 (spk1 @ W2.T + b2, wave-per-row)
//        -> scan2 (layer-2 membrane recursion -> out)

#define T_STEPS 50
#define BATCH   128
#define NI      16384
#define NH      256
#define NO      11
#define M_TOT   (T_STEPS * BATCH)   // 6400
#define KSPLIT  8
#define KCHUNK  (NI / KSPLIT)       // 2048
#define BK      32
#define KTILES  (KCHUNK / BK)       // 64
#define BM      128
#define BN      256

typedef _Float16 f16x8 __attribute__((ext_vector_type(8)));
typedef _Float16 f16x4 __attribute__((ext_vector_type(4)));
typedef float    f32x4 __attribute__((ext_vector_type(4)));

__device__ __forceinline__ void split2(float f, _Float16& hi, _Float16& lo) {
    hi = (_Float16)f;                 // RN
    lo = (_Float16)(f - (float)hi);   // exact residual, then RN -> ~2^-24 total
}

// LDS tiles are [rows][BK=32] f16 (64B rows). Unswizzled fragment reads are an
// 8-way bank conflict (lane bank = 4q + 16*(l15&1)). XOR the 16B-block index
// with ((row>>1)&3): per 16-lane phase both reads and writes then cover all
// 32 banks exactly 2 dwords deep -> conflict-free.
__device__ __forceinline__ int swz(int row, int blk) {
    return row * BK + ((blk ^ ((row >> 1) & 3)) << 3);
}

typedef __attribute__((address_space(1))) const unsigned int guint;
typedef __attribute__((address_space(3))) unsigned int luint;
__device__ __forceinline__ void lds16(const void* g, void* l) {
    // async 16B/lane global->LDS DMA; LDS dest = wave-uniform base + lane*16
    __builtin_amdgcn_global_load_lds((guint*)g, (luint*)l, 16, 0, 0);
}

// ---------------------------------------------------------------------------
// one-time W1 fp32 -> f16 hi/lo limbs (bitwise identical to per-tile split2)
// ---------------------------------------------------------------------------
__global__ __launch_bounds__(256) void convert_w1(
    const float* __restrict__ W1, _Float16* __restrict__ Wh, _Float16* __restrict__ Wl)
{
    const size_t i = ((size_t)blockIdx.x * 256 + threadIdx.x) * 4;
    const float4 v = *(const float4*)(W1 + i);
    float a[4] = { v.x, v.y, v.z, v.w };
    f16x4 h, l;
#pragma unroll
    for (int j = 0; j < 4; ++j) {
        _Float16 hh, ll;
        split2(a[j], hh, ll);
        h[j] = hh; l[j] = ll;
    }
    *(f16x4*)(Wh + i) = h;
    *(f16x4*)(Wl + i) = l;
}

// ---------------------------------------------------------------------------
// gemm1: part[ks][m][n] = sum_{k in chunk ks} X[m][k] * W1[n][k]
// 128x256 block tile, 4 waves of 64x128, 16x16x32 f16 MFMA, 3 limb products.
// A: fp32 load -> reg split2 -> swizzled ds_write.
// B: preconverted f16 limbs, global_load_lds with inverse-swizzled per-lane
//    global source (linear LDS dest; source perm == read perm, an involution).
// ---------------------------------------------------------------------------
__global__ __launch_bounds__(256, 2) void gemm1_mfma(
    const float* __restrict__ X, const _Float16* __restrict__ W1h,
    const _Float16* __restrict__ W1l, float* __restrict__ part)
{
    __shared__ alignas(16) _Float16 Ah[BM * BK];   // 8 KB
    __shared__ alignas(16) _Float16 Al[BM * BK];   // 8 KB
    __shared__ alignas(16) _Float16 Bh[BN * BK];   // 16 KB
    __shared__ alignas(16) _Float16 Bl[BN * BK];   // 16 KB

    const int tid  = threadIdx.x;
    const int lane = tid & 63;
    const int wave = tid >> 6;
    const int wm   = wave >> 1;       // 0..1 : m offset 64*wm
    const int wn   = wave & 1;        // 0..1 : n offset 128*wn
    const int q    = lane >> 4;       // quad 0..3
    const int l15  = lane & 15;

    const int m0 = blockIdx.x * BM;   // 0..6272
    const int ks = blockIdx.y;        // 0..7
    const int kbase = ks * KCHUNK;

    // A staging assignment: thread covers rows tid>>2 and 64+(tid>>2), 8-float group tid&3
    const int a_row[2] = { tid >> 2, 64 + (tid >> 2) };
    const int a_g8     = tid & 3;

    // B DMA: wave w, instr j covers rows [w*64+j*16, +16). lane i stores LDS
    // slot (row = base+(i>>2), block = i&3); it must FETCH global block
    // (i&3) ^ ((row>>1)&3) so that the LDS content is the swizzled layout.
    int b_row[4], b_fb[4];
#pragma unroll
    for (int j = 0; j < 4; ++j) {
        b_row[j] = wave * 64 + j * 16 + (lane >> 2);
        b_fb[j]  = (lane & 3) ^ ((b_row[j] >> 1) & 3);
    }

    f32x4 acc[4][8];
#pragma unroll
    for (int im = 0; im < 4; ++im)
#pragma unroll
        for (int jn = 0; jn < 8; ++jn) acc[im][jn] = (f32x4){0.f, 0.f, 0.f, 0.f};

    // fragment-read swizzle: row = (16-mult) + l15 -> ((row>>1)&3) == ((l15>>1)&3)
    const int xsw = (l15 >> 1) & 3;
    const int qx  = (q ^ xsw) << 3;

    for (int kt = 0; kt < KTILES; ++kt) {
        const int k0 = kbase + kt * BK;

        // ---- A: global fp32 loads + limb conversion (regs, pre-barrier) ----
        f16x8 ahv[2], alv[2];
#pragma unroll
        for (int i = 0; i < 2; ++i) {
            const float* s = X + (size_t)(m0 + a_row[i]) * NI + k0 + a_g8 * 8;
            const float4 v0 = *(const float4*)s, v1 = *(const float4*)(s + 4);
            float av[8] = { v0.x, v0.y, v0.z, v0.w, v1.x, v1.y, v1.z, v1.w };
#pragma unroll
            for (int j = 0; j < 8; ++j) { _Float16 h, l; split2(av[j], h, l); ahv[i][j] = h; alv[i][j] = l; }
        }

        __syncthreads();   // all waves done reading previous tile

        // ---- B: async DMA into linear LDS (content pre-swizzled via source) ----
#pragma unroll
        for (int j = 0; j < 4; ++j) {
            const size_t goff = (size_t)b_row[j] * NI + k0 + b_fb[j] * 8;
            const int lbase = (wave * 4 + j) * 512;   // 16 rows * 32 f16
            lds16(W1h + goff, &Bh[lbase]);
            lds16(W1l + goff, &Bl[lbase]);
        }

        // ---- A: swizzled LDS stores ----
#pragma unroll
        for (int i = 0; i < 2; ++i) {
            const int off = swz(a_row[i], a_g8);
            *(f16x8*)&Ah[off] = ahv[i];
            *(f16x8*)&Al[off] = alv[i];
        }

        __syncthreads();   // staging + DMA visible (vmcnt+lgkm drained)

        // ---- fragments + MFMA ----
        // A[m = l15][k = q*8+j], B^T[n = l15][k = q*8+j]; D: row=q*4+r, col=l15
        f16x8 fah[4], fal[4];
#pragma unroll
        for (int im = 0; im < 4; ++im) {
            const int off = (64 * wm + 16 * im + l15) * BK + qx;
            fah[im] = *(const f16x8*)&Ah[off];
            fal[im] = *(const f16x8*)&Al[off];
        }
        // jn-outer with per-jn B fragments: ~210 live VGPRs instead of ~270
#pragma unroll
        for (int jn = 0; jn < 8; ++jn) {
            const int off = (128 * wn + 16 * jn + l15) * BK + qx;
            const f16x8 fbh = *(const f16x8*)&Bh[off];
            const f16x8 fbl = *(const f16x8*)&Bl[off];
#pragma unroll
            for (int im = 0; im < 4; ++im) {
                acc[im][jn] = __builtin_amdgcn_mfma_f32_16x16x32_f16(fah[im], fbh, acc[im][jn], 0, 0, 0);
                acc[im][jn] = __builtin_amdgcn_mfma_f32_16x16x32_f16(fal[im], fbh, acc[im][jn], 0, 0, 0);
                acc[im][jn] = __builtin_amdgcn_mfma_f32_16x16x32_f16(fah[im], fbl, acc[im][jn], 0, 0, 0);
            }
        }
    }

    // ---- epilogue: write fp32 partials ----
    float* P = part + (size_t)ks * M_TOT * NH;
#pragma unroll
    for (int im = 0; im < 4; ++im) {
        const int mrow = m0 + 64 * wm + 16 * im + 4 * q;
#pragma unroll
        for (int jn = 0; jn < 8; ++jn) {
            const int n = 128 * wn + 16 * jn + l15;
#pragma unroll
            for (int r = 0; r < 4; ++r)
                P[(size_t)(mrow + r) * NH + n] = acc[im][jn][r];
        }
    }
}

// split-K reduce + bias + layer-1 membrane recursion; emits spk1
__global__ __launch_bounds__(256) void scan1_kernel(
    const float* __restrict__ part, const float* __restrict__ b1,
    float* __restrict__ spk1)
{
    const int b = blockIdx.x;    // 0..127
    const int h = threadIdx.x;   // 0..255
    const float bias = b1[h];
    const size_t S = (size_t)M_TOT * NH;
    float mem = 0.f;
    for (int t = 0; t < T_STEPS; ++t) {
        const size_t idx = ((size_t)(t * BATCH + b)) * NH + h;
        float c = ((part[idx] + part[S + idx]) + (part[2 * S + idx] + part[3 * S + idx]))
                + ((part[4 * S + idx] + part[5 * S + idx]) + (part[6 * S + idx] + part[7 * S + idx]));
        c += bias;
        mem = __fadd_rn(__fmul_rn(0.9f, mem), c);
        const float s = (mem > 1.0f) ? 1.0f : 0.0f;
        mem -= s;
        spk1[idx] = s;
    }
}

// cur2 = spk1 @ W2.T + b2 ; wave-per-row, shfl-xor tree reduction (K=256)
__global__ __launch_bounds__(256) void gemm2_kernel(
    const float* __restrict__ spk1, const float* __restrict__ W2,
    const float* __restrict__ b2, float* __restrict__ cur2)
{
    const int wave = threadIdx.x >> 6;
    const int lane = threadIdx.x & 63;
    const int m = blockIdx.x * 4 + wave;   // 0..6399
    const float4 s4 = *(const float4*)(spk1 + (size_t)m * NH + (lane << 2));
#pragma unroll
    for (int o = 0; o < NO; ++o) {
        const float4 w4 = *(const float4*)(W2 + (size_t)o * NH + (lane << 2));
        float p = (s4.x * w4.x + s4.y * w4.y) + (s4.z * w4.z + s4.w * w4.w);
#pragma unroll
        for (int d = 32; d; d >>= 1) p += __shfl_xor(p, d, 64);
        if (lane == 0) cur2[(size_t)m * 16 + o] = p + b2[o];
    }
}

// layer-2 membrane recursion; emits spk2 = final output
__global__ __launch_bounds__(256) void scan2_kernel(
    const float* __restrict__ cur2, float* __restrict__ out)
{
    const int tid = blockIdx.x * 256 + threadIdx.x;
    if (tid >= BATCH * NO) return;
    const int b = tid / NO, o = tid % NO;
    float mem = 0.f;
    for (int t = 0; t < T_STEPS; ++t) {
        const float c = cur2[(size_t)(t * BATCH + b) * 16 + o];
        mem = __fadd_rn(__fmul_rn(0.9f, mem), c);
        const float s = (mem > 1.0f) ? 1.0f : 0.0f;
        mem -= s;
        out[(size_t)(t * BATCH + b) * NO + o] = s;
    }
}

extern "C" void kernel_launch(void* const* d_in, const int* in_sizes, int n_in,
                              void* d_out, int out_size, void* d_ws, size_t ws_size,
                              hipStream_t stream) {
    const float* x  = (const float*)d_in[0];   // [50,128,128,128]
    const float* W1 = (const float*)d_in[1];   // [256,16384]
    const float* b1 = (const float*)d_in[2];   // [256]
    const float* W2 = (const float*)d_in[3];   // [11,256]
    const float* b2 = (const float*)d_in[4];   // [11]
    float* out = (float*)d_out;                // [50,128,11]

    float* part = (float*)d_ws;                          // 8 * 6400*256 fp32 = 52.4 MB
    float* spk1 = part + (size_t)KSPLIT * M_TOT * NH;    // 6.55 MB
    float* cur2 = spk1 + (size_t)M_TOT * NH;             // 6400*16 fp32 = 0.41 MB
    _Float16* W1h = (_Float16*)(cur2 + (size_t)M_TOT * 16);  // 8 MB
    _Float16* W1l = W1h + (size_t)NH * NI;                   // 8 MB

    convert_w1<<<(NH * NI) / (256 * 4), 256, 0, stream>>>(W1, W1h, W1l);
    dim3 g1(M_TOT / BM, KSPLIT);                         // (50, 8)
    gemm1_mfma<<<g1, 256, 0, stream>>>(x, W1h, W1l, part);
    scan1_kernel<<<BATCH, NH, 0, stream>>>(part, b1, spk1);
    gemm2_kernel<<<M_TOT / 4, 256, 0, stream>>>(spk1, W2, b2, cur2);
    scan2_kernel<<<(BATCH * NO + 255) / 256, 256, 0, stream>>>(cur2, out);
}